// Round 1
// 1222.902 us; speedup vs baseline: 1.0196x; 1.0196x over previous
//
#include <hip/hip_runtime.h>

// Residual VQ forward, MFMA candidates + R3-replica exact selection. R9:
//  - XCD-pinned block swizzle in k_gemm_topk: all 16 column-blocks of one
//    row-panel (mb) land on ONE XCD (L%8 == HW round-robin), so the A panel
//    is L2-resident after first touch (FETCH was 3.8x ideal -> staging loads
//    paid HBM/L3 latency against a 1-iter prefetch depth).
//  - top-4 epilogue loop unrolled (pipelines the 32 ds_read_b32s; insertion
//    order preserved -> bit-exact).
// R8: LDS 34304, 4 blocks/CU, in-wave shuffle top-4 merge, k_init+k_cvt merged.
// d_out flat: [quantized (B,T,D) | indices (B,T,Q) as float | loss scalar]
// Selection arithmetic (validated R3/R5/R6/R7, bit-exact vs reference):
//   sb = c2 - 2*dot_bf16 candidates (top-4 per 128-code block);
//   exact rescore = ascending 512-step fmaf chain, s = fl(fl(r2-2d)+c2),
//   contract off, lowest-index tie-break; r2/c2 numpy-pairwise order.

constexpr int DIM   = 512;
constexpr int KCB   = 2048;
constexpr int NQ    = 8;
constexpr int NTOK  = 8 * 2048;       // 16384
constexpr int QELEM = NTOK * DIM;     // 8388608
constexpr int NBLK  = KCB / 128;      // 16 column blocks
constexpr float WINDOW = 1e-3f;       // worst-case bf16 score err ~4.5e-4

using short8  = __attribute__((ext_vector_type(8))) short;
using float4v = __attribute__((ext_vector_type(4))) float;

__device__ __forceinline__ unsigned short f2bf(float f) {
    unsigned u = __float_as_uint(f);
    return (unsigned short)((u + 0x7FFFu + ((u >> 16) & 1u)) >> 16);   // RNE
}

__device__ __forceinline__ void gl2lds16(const void* g, void* l) {
    __builtin_amdgcn_global_load_lds(
        (__attribute__((address_space(1))) void*)g,
        (__attribute__((address_space(3))) void*)l, 16, 0, 0);
}

struct Top4 { float s[4]; int i[4]; };
__device__ __forceinline__ void t4_init(Top4& t) {
#pragma unroll
    for (int j = 0; j < 4; ++j) { t.s[j] = 3.0e38f; t.i[j] = 0x7FFFFFFF; }
}
__device__ __forceinline__ void t4_ins(Top4& t, float s, int idx) {
    if (s < t.s[3]) {
        if (s < t.s[2]) { t.s[3] = t.s[2]; t.i[3] = t.i[2];
            if (s < t.s[1]) { t.s[2] = t.s[1]; t.i[2] = t.i[1];
                if (s < t.s[0]) { t.s[1] = t.s[0]; t.i[1] = t.i[0]; t.s[0] = s; t.i[0] = idx; }
                else            { t.s[1] = s; t.i[1] = idx; }
            } else { t.s[2] = s; t.i[2] = idx; }
        } else { t.s[3] = s; t.i[3] = idx; }
    }
}

// fused: copy x->R, cast x->Rb, cast codebooks->Cbb
__global__ void k_initcvt(const float4* __restrict__ x, const float4* __restrict__ cbs,
                          float4* __restrict__ R, ushort4* __restrict__ Rb,
                          ushort4* __restrict__ Cbb)
{
    int i = blockIdx.x * blockDim.x + threadIdx.x;
    constexpr int N4 = QELEM / 4;
    if (i < N4) {
        float4 v = x[i];
        R[i] = v;
        Rb[i] = make_ushort4(f2bf(v.x), f2bf(v.y), f2bf(v.z), f2bf(v.w));
    } else {
        int j = i - N4;
        float4 v = cbs[j];
        Cbb[j] = make_ushort4(f2bf(v.x), f2bf(v.y), f2bf(v.z), f2bf(v.w));
    }
}

// numpy-pairwise sum of squares per row (n=512): verified bit-compatible (R3).
__global__ __launch_bounds__(256) void k_sqnorm_np(const float* __restrict__ A,
                                                   float* __restrict__ out)
{
#pragma clang fp contract(off)
    __shared__ float buf[4][DIM];
    __shared__ float accs[4][32];
    const int w = threadIdx.x >> 6, lane = threadIdx.x & 63;
    const int row = blockIdx.x * 4 + w;

    const float4* a4 = reinterpret_cast<const float4*>(A + (size_t)row * DIM);
    float4* b4 = reinterpret_cast<float4*>(buf[w]);
    b4[lane]      = a4[lane];
    b4[lane + 64] = a4[lane + 64];
    __syncthreads();
    if (lane < 32) {
        int blk = lane >> 3, j = lane & 7;
        const float* p = buf[w] + blk * 128 + j;
        float x0 = p[0];
        float acc = x0 * x0;
#pragma unroll
        for (int m = 1; m < 16; ++m) { float x = p[8 * m]; acc = acc + x * x; }
        accs[w][lane] = acc;
    }
    __syncthreads();
    if (lane == 0) {
        float B[4];
#pragma unroll
        for (int blk = 0; blk < 4; ++blk) {
            const float* r = &accs[w][blk * 8];
            B[blk] = ((r[0] + r[1]) + (r[2] + r[3])) + ((r[4] + r[5]) + (r[6] + r[7]));
        }
        out[row] = (B[0] + B[1]) + (B[2] + B[3]);
    }
}

// 128x128 tile bf16 MFMA GEMM (A.B^T) + per-row top-4 over the 128 cols.
// Fragment-ordered LDS (conflict-free), double-buffered staging, slim LDS.
// R9: XCD-pinned swizzle -- all nb-blocks of one mb on the same XCD so the
// A panel (128KB) stays L2-resident across its 16 reuses.
__global__ __launch_bounds__(256, 4) void k_gemm_topk(
        const unsigned short* __restrict__ Rb, const unsigned short* __restrict__ Cbb,
        const float* __restrict__ c2, float* __restrict__ candS, int* __restrict__ candI)
{
    // [0,32768): A0|A1|B0|B1 (8KB each, K-loop dbuf).
    // Epilogue: scb fp32 [64][132] at 0 (33792B, aliases dbuf).
    // c2s fp32[128] at 33792 (outside dbuf -> survives K-loop). Total 34304.
    __shared__ __align__(16) char smem[34304];
    unsigned short* A0 = (unsigned short*)smem;                   // 4096 shorts
    unsigned short* B0 = (unsigned short*)(smem + 16384);
    float*  scb = (float*)smem;
    float*  c2s = (float*)(smem + 33792);

    const int tid  = threadIdx.x;
    const int wid  = tid >> 6, lane = tid & 63;
    const int quad = lane >> 4, l16 = lane & 15;

    // dispatch-linear id (x fastest); HW round-robins XCD by L%8.
    // mb = (L&7)*16 + (L>>3)/16  -> each XCD owns 16 consecutive mb panels,
    // nb = (L>>3)&15             -> nb iterates fastest within an XCD.
    // Bijective on [0,2048); grid % 8 == 0.
    const int L    = blockIdx.y * NBLK + blockIdx.x;
    const int slot = L >> 3;
    const int mb   = (L & 7) * 16 + (slot >> 4);
    const int nb   = slot & 15;

    const int tok0 = mb * 128, n0 = nb * 128;
    const int nw = (wid & 1) * 64;
    const int fbA = (wid >> 1) * 4;      // base mi for this wave's A rows
    const int fbB = (wid & 1) * 4;       // base nj for this wave's B rows

    if (tid < 128) c2s[tid] = c2[n0 + tid];

    float4v acc[4][4];
    float4v zero = {0.f, 0.f, 0.f, 0.f};
#pragma unroll
    for (int mi = 0; mi < 4; ++mi)
#pragma unroll
        for (int nj = 0; nj < 4; ++nj) acc[mi][nj] = zero;

    // stage tile kb into buffer b: lane (quad,l16) of wave wid loads
    // row (i*4+wid)*16+l16, k-chunk quad -> LDS unit i*256+wid*64+lane.
    auto stage = [&](int b, int kb) {
        unsigned short* Ad = A0 + b * 4096;
        unsigned short* Bd = B0 + b * 4096;
#pragma unroll
        for (int i = 0; i < 2; ++i) {
            int mi_abs = i * 4 + wid;
            gl2lds16(&Rb[(size_t)(tok0 + mi_abs * 16 + l16) * DIM + kb + quad * 8],
                     Ad + (size_t)(i * 256 + wid * 64) * 8);
            gl2lds16(&Cbb[(size_t)(n0 + mi_abs * 16 + l16) * DIM + kb + quad * 8],
                     Bd + (size_t)(i * 256 + wid * 64) * 8);
        }
    };

    stage(0, 0);
    for (int it = 0; it < 16; ++it) {
        __syncthreads();                       // buf[it&1] ready (vmcnt drain)
        if (it < 15) stage((it + 1) & 1, (it + 1) * 32);
        const unsigned short* Ac = A0 + (it & 1) * 4096;
        const unsigned short* Bc = B0 + (it & 1) * 4096;
        short8 af[4], bf[4];
#pragma unroll
        for (int mi = 0; mi < 4; ++mi)
            af[mi] = *(const short8*)(Ac + ((size_t)(fbA + mi) * 64 + lane) * 8);
#pragma unroll
        for (int nj = 0; nj < 4; ++nj)
            bf[nj] = *(const short8*)(Bc + ((size_t)(fbB + nj) * 64 + lane) * 8);
#pragma unroll
        for (int mi = 0; mi < 4; ++mi)
#pragma unroll
            for (int nj = 0; nj < 4; ++nj)
                acc[mi][nj] = __builtin_amdgcn_mfma_f32_16x16x32_bf16(
                    af[mi], bf[nj], acc[mi][nj], 0, 0, 0);
    }

    // epilogue: two 64-row halves; per-row top-4 of sb = c2 - 2*dot.
    // scb stride 132: write bank 16(quad+nj)+4e+l16, read bank 4row+part ->
    // both 2 lanes/bank (free). Part-merge via in-wave shuffles (no LDS).
    for (int h = 0; h < 2; ++h) {
        __syncthreads();
        if ((wid >> 1) == h) {
#pragma unroll
            for (int mi = 0; mi < 4; ++mi)
#pragma unroll
                for (int nj = 0; nj < 4; ++nj) {
                    int r0 = mi * 16 + quad * 4;
                    int cc = nw + nj * 16 + l16;
#pragma unroll
                    for (int e = 0; e < 4; ++e)
                        scb[(r0 + e) * 132 + cc] = acc[mi][nj][e];
                }
        }
        __syncthreads();
        int row = tid >> 2, part = tid & 3;
        Top4 t; t4_init(t);
#pragma unroll
        for (int i = 0; i < 32; ++i) {
            int col = part + 4 * i;
            float s = c2s[col] - 2.0f * scb[row * 132 + col];
            t4_ins(t, s, n0 + col);
        }
        // merge the 4 parts of this row (4 adjacent lanes of one wave)
#pragma unroll
        for (int k = 1; k <= 2; k <<= 1) {
            float os[4]; int oi[4];
#pragma unroll
            for (int j = 0; j < 4; ++j) {
                os[j] = __shfl_xor(t.s[j], k, 64);
                oi[j] = __shfl_xor(t.i[j], k, 64);
            }
#pragma unroll
            for (int j = 0; j < 4; ++j) t4_ins(t, os[j], oi[j]);
        }
        if (part == 0) {
            int token = tok0 + h * 64 + row;
            size_t base = (size_t)token * 64 + (size_t)nb * 4;
#pragma unroll
            for (int j = 0; j < 4; ++j) { candS[base + j] = t.s[j]; candI[base + j] = t.i[j]; }
        }
    }
}

// Fused: select winner (R3-replica exact rescore of in-window candidates),
// update residual, recast bf16, np-ordered r2 for next level, loss partial.
// Last level: write quantized = x - r_new directly.
__global__ __launch_bounds__(256) void k_selupd(
        const float* __restrict__ candS, const int* __restrict__ candI,
        float* __restrict__ R, const float* __restrict__ cbf,
        float* __restrict__ r2, const float* __restrict__ c2,
        float* __restrict__ idx_out, float* __restrict__ partial,
        ushort4* __restrict__ Rb, const float4* __restrict__ x, int level)
{
#pragma clang fp contract(off)
    __shared__ float buf[4][DIM];
    __shared__ float accs[4][32];
    __shared__ float shl[4];
    const int w = threadIdx.x >> 6, lane = threadIdx.x & 63;
    const int t = blockIdx.x * 4 + w;
    const bool last = (level == NQ - 1);

    // ---- select ----
    float sb = candS[(size_t)t * 64 + lane];
    int   ci = candI[(size_t)t * 64 + lane];
    float mn = sb;
#pragma unroll
    for (int off = 32; off; off >>= 1) mn = fminf(mn, __shfl_xor(mn, off, 64));
    unsigned long long mask = __ballot(sb <= mn + WINDOW);
    int ncand = __popcll(mask);
    int winner;
    if (ncand == 1) {
        winner = __shfl(ci, __ffsll(mask) - 1, 64);
    } else {
        int src = 0;
        if (lane < ncand) {
            unsigned long long mm = mask;
            for (int z = 0; z < lane; ++z) mm &= mm - 1;
            src = __ffsll(mm) - 1;
        }
        int cidx = __shfl(ci, src, 64);
        float s = 3.0e38f;
        int   si = 0x7FFFFFFF;
        if (lane < ncand) {
            const float* rp = R   + (size_t)t    * DIM;
            const float* cp = cbf + (size_t)cidx * DIM;
            float d = 0.f;
#pragma unroll 8
            for (int k = 0; k < DIM; ++k) d = fmaf(rp[k], cp[k], d);
            float td = 2.0f * d;
            float a  = r2[t] - td;
            s  = a + c2[cidx];
            si = cidx;
        }
#pragma unroll
        for (int off = 32; off; off >>= 1) {
            float ov = __shfl_xor(s, off, 64);
            int   oi = __shfl_xor(si, off, 64);
            if (ov < s || (ov == s && oi < si)) { s = ov; si = oi; }
        }
        winner = si;
    }
    if (lane == 0) idx_out[(size_t)t * NQ + level] = (float)winner;

    // ---- update ----
    const float4* c4 = reinterpret_cast<const float4*>(cbf + (size_t)winner * DIM);
    float4*       r4 = reinterpret_cast<float4*>(R + (size_t)t * DIM);
    float4*       b4 = reinterpret_cast<float4*>(buf[w]);
    float ls = 0.f;
#pragma unroll
    for (int i = 0; i < 2; ++i) {
        int d = lane + 64 * i;
        float4 rv = r4[d], cv = c4[d];
        rv.x -= cv.x; rv.y -= cv.y; rv.z -= cv.z; rv.w -= cv.w;
        ls = ls + rv.x * rv.x; ls = ls + rv.y * rv.y;
        ls = ls + rv.z * rv.z; ls = ls + rv.w * rv.w;
        if (!last) {
            r4[d] = rv;
            b4[d] = rv;
            Rb[(size_t)t * 128 + d] = make_ushort4(f2bf(rv.x), f2bf(rv.y),
                                                   f2bf(rv.z), f2bf(rv.w));
        } else {
            float4 xv = x[(size_t)t * 128 + d];
            xv.x -= rv.x; xv.y -= rv.y; xv.z -= rv.z; xv.w -= rv.w;
            r4[d] = xv;                       // quantized = x - r_final (in d_out)
        }
    }

    if (!last) {
        __syncthreads();
        // np-pairwise r2 of the NEW residual (same order as k_sqnorm_np)
        if (lane < 32) {
            int blk = lane >> 3, j = lane & 7;
            const float* p = buf[w] + blk * 128 + j;
            float x0 = p[0];
            float acc = x0 * x0;
#pragma unroll
            for (int m = 1; m < 16; ++m) { float xx = p[8 * m]; acc = acc + xx * xx; }
            accs[w][lane] = acc;
        }
        __syncthreads();
        if (lane == 0) {
            float B[4];
#pragma unroll
            for (int blk = 0; blk < 4; ++blk) {
                const float* r = &accs[w][blk * 8];
                B[blk] = ((r[0] + r[1]) + (r[2] + r[3])) + ((r[4] + r[5]) + (r[6] + r[7]));
            }
            r2[t] = (B[0] + B[1]) + (B[2] + B[3]);
        }
    }

    // ---- loss partial ----
#pragma unroll
    for (int off = 32; off; off >>= 1) ls += __shfl_down(ls, off, 64);
    if (lane == 0) shl[w] = ls;
    __syncthreads();
    if (threadIdx.x == 0) partial[blockIdx.x] = (shl[0] + shl[1]) + (shl[2] + shl[3]);
}

__global__ __launch_bounds__(256) void k_finalize_loss(const float* __restrict__ partial,
                                                       float* __restrict__ loss_out)
{
    double s = 0.0;
    for (int i = threadIdx.x; i < NQ * (NTOK / 4); i += 256) s += (double)partial[i];
#pragma unroll
    for (int off = 32; off; off >>= 1) s += __shfl_down(s, off, 64);
    __shared__ double sh[4];
    if ((threadIdx.x & 63) == 0) sh[threadIdx.x >> 6] = s;
    __syncthreads();
    if (threadIdx.x == 0) {
        double tot = (sh[0] + sh[1]) + (sh[2] + sh[3]);
        loss_out[0] = (float)(tot * 1.25 / ((double)NQ * (double)QELEM));
    }
}

extern "C" void kernel_launch(void* const* d_in, const int* in_sizes, int n_in,
                              void* d_out, int out_size, void* d_ws, size_t ws_size,
                              hipStream_t stream)
{
    const float* x   = (const float*)d_in[0];
    const float* cbs = (const float*)d_in[1];

    float* qout     = (float*)d_out;
    float* idx_out  = qout + QELEM;
    float* loss_out = idx_out + (size_t)NTOK * NQ;
    float* R        = qout;                 // residual lives in d_out (validated R5)

    char* ws = (char*)d_ws;
    size_t off = 0;
    unsigned short* Rb   = (unsigned short*)(ws + off); off += (size_t)QELEM * 2;  // 16MB
    unsigned short* Cbb  = (unsigned short*)(ws + off); off += (size_t)QELEM * 2;  // 16MB
    float*          c2   = (float*)(ws + off);          off += (size_t)NQ * KCB * 4;
    float*          r2   = (float*)(ws + off);          off += (size_t)NTOK * 4;
    float*          part = (float*)(ws + off);          off += (size_t)NQ * (NTOK / 4) * 4;
    float*          candS= (float*)(ws + off);          off += (size_t)NTOK * 64 * 4; // 4MB
    int*            candI= (int*)(ws + off);            off += (size_t)NTOK * 64 * 4; // 4MB

    k_initcvt<<<2 * (QELEM / 4) / 256, 256, 0, stream>>>((const float4*)x, (const float4*)cbs,
                                                         (float4*)R, (ushort4*)Rb,
                                                         (ushort4*)Cbb);
    k_sqnorm_np<<<NQ * KCB / 4, 256, 0, stream>>>(cbs, c2);
    k_sqnorm_np<<<NTOK / 4, 256, 0, stream>>>(R, r2);   // r2 of x for level 0

    for (int q = 0; q < NQ; ++q) {
        const float*          cbq  = cbs + (size_t)q * KCB * DIM;
        const unsigned short* cbbq = Cbb + (size_t)q * KCB * DIM;
        const float*          c2q  = c2 + (size_t)q * KCB;
        dim3 g(NBLK, NTOK / 128);
        k_gemm_topk<<<g, 256, 0, stream>>>(Rb, cbbq, c2q, candS, candI);
        k_selupd<<<NTOK / 4, 256, 0, stream>>>(candS, candI, R, cbq, r2, c2q,
                                               idx_out, part + (size_t)q * (NTOK / 4),
                                               (ushort4*)Rb, (const float4*)x, q);
    }

    k_finalize_loss<<<1, 256, 0, stream>>>(part, loss_out);
}

// Round 2
// 1041.356 us; speedup vs baseline: 1.1974x; 1.1743x over previous
//
#include <hip/hip_runtime.h>

// Residual VQ forward, MFMA candidates + R3-replica exact selection. R10:
//  - k_gemm_topk: counted-vmcnt triple-buffer K-loop (T4). stage(it+2) issued
//    after the barrier; wait only vmcnt(4) so next tile's loads stay in flight
//    across the barrier (old __syncthreads drained vmcnt(0) every iter).
//    LDS 49664 -> 3 blocks/CU (matches measured effective occupancy).
//  - k_selupd: R row staged once (coalesced float4 -> LDS + regs); rescore
//    reads rp from LDS (broadcast) and cp as float4; update reuses regs.
//    Same fmaf chain order/values -> bit-exact.
// R9: XCD-pinned swizzle (FETCH 67.7->16.6MB, ~ideal). R8: slim LDS, shuffle
// top-4 merge.
// d_out flat: [quantized (B,T,D) | indices (B,T,Q) as float | loss scalar]
// Selection arithmetic (validated R3/R5/R6/R7, bit-exact vs reference):
//   sb = c2 - 2*dot_bf16 candidates (top-4 per 128-code block);
//   exact rescore = ascending 512-step fmaf chain, s = fl(fl(r2-2d)+c2),
//   contract off, lowest-index tie-break; r2/c2 numpy-pairwise order.

constexpr int DIM   = 512;
constexpr int KCB   = 2048;
constexpr int NQ    = 8;
constexpr int NTOK  = 8 * 2048;       // 16384
constexpr int QELEM = NTOK * DIM;     // 8388608
constexpr int NBLK  = KCB / 128;      // 16 column blocks
constexpr float WINDOW = 1e-3f;       // worst-case bf16 score err ~4.5e-4

using short8  = __attribute__((ext_vector_type(8))) short;
using float4v = __attribute__((ext_vector_type(4))) float;

__device__ __forceinline__ unsigned short f2bf(float f) {
    unsigned u = __float_as_uint(f);
    return (unsigned short)((u + 0x7FFFu + ((u >> 16) & 1u)) >> 16);   // RNE
}

__device__ __forceinline__ void gl2lds16(const void* g, void* l) {
    __builtin_amdgcn_global_load_lds(
        (__attribute__((address_space(1))) void*)g,
        (__attribute__((address_space(3))) void*)l, 16, 0, 0);
}

struct Top4 { float s[4]; int i[4]; };
__device__ __forceinline__ void t4_init(Top4& t) {
#pragma unroll
    for (int j = 0; j < 4; ++j) { t.s[j] = 3.0e38f; t.i[j] = 0x7FFFFFFF; }
}
__device__ __forceinline__ void t4_ins(Top4& t, float s, int idx) {
    if (s < t.s[3]) {
        if (s < t.s[2]) { t.s[3] = t.s[2]; t.i[3] = t.i[2];
            if (s < t.s[1]) { t.s[2] = t.s[1]; t.i[2] = t.i[1];
                if (s < t.s[0]) { t.s[1] = t.s[0]; t.i[1] = t.i[0]; t.s[0] = s; t.i[0] = idx; }
                else            { t.s[1] = s; t.i[1] = idx; }
            } else { t.s[2] = s; t.i[2] = idx; }
        } else { t.s[3] = s; t.i[3] = idx; }
    }
}

// fused: copy x->R, cast x->Rb, cast codebooks->Cbb
__global__ void k_initcvt(const float4* __restrict__ x, const float4* __restrict__ cbs,
                          float4* __restrict__ R, ushort4* __restrict__ Rb,
                          ushort4* __restrict__ Cbb)
{
    int i = blockIdx.x * blockDim.x + threadIdx.x;
    constexpr int N4 = QELEM / 4;
    if (i < N4) {
        float4 v = x[i];
        R[i] = v;
        Rb[i] = make_ushort4(f2bf(v.x), f2bf(v.y), f2bf(v.z), f2bf(v.w));
    } else {
        int j = i - N4;
        float4 v = cbs[j];
        Cbb[j] = make_ushort4(f2bf(v.x), f2bf(v.y), f2bf(v.z), f2bf(v.w));
    }
}

// numpy-pairwise sum of squares per row (n=512): verified bit-compatible (R3).
__global__ __launch_bounds__(256) void k_sqnorm_np(const float* __restrict__ A,
                                                   float* __restrict__ out)
{
#pragma clang fp contract(off)
    __shared__ float buf[4][DIM];
    __shared__ float accs[4][32];
    const int w = threadIdx.x >> 6, lane = threadIdx.x & 63;
    const int row = blockIdx.x * 4 + w;

    const float4* a4 = reinterpret_cast<const float4*>(A + (size_t)row * DIM);
    float4* b4 = reinterpret_cast<float4*>(buf[w]);
    b4[lane]      = a4[lane];
    b4[lane + 64] = a4[lane + 64];
    __syncthreads();
    if (lane < 32) {
        int blk = lane >> 3, j = lane & 7;
        const float* p = buf[w] + blk * 128 + j;
        float x0 = p[0];
        float acc = x0 * x0;
#pragma unroll
        for (int m = 1; m < 16; ++m) { float x = p[8 * m]; acc = acc + x * x; }
        accs[w][lane] = acc;
    }
    __syncthreads();
    if (lane == 0) {
        float B[4];
#pragma unroll
        for (int blk = 0; blk < 4; ++blk) {
            const float* r = &accs[w][blk * 8];
            B[blk] = ((r[0] + r[1]) + (r[2] + r[3])) + ((r[4] + r[5]) + (r[6] + r[7]));
        }
        out[row] = (B[0] + B[1]) + (B[2] + B[3]);
    }
}

// 128x128 tile bf16 MFMA GEMM (A.B^T) + per-row top-4 over the 128 cols.
// R10: triple-buffered staging with counted vmcnt(4) -- next tile's loads stay
// in flight across the barrier instead of being drained by __syncthreads.
__global__ __launch_bounds__(256, 3) void k_gemm_topk(
        const unsigned short* __restrict__ Rb, const unsigned short* __restrict__ Cbb,
        const float* __restrict__ c2, float* __restrict__ candS, int* __restrict__ candI)
{
    // [0,24576): A0|A1|A2 (8KB each).  [24576,49152): B0|B1|B2.
    // Epilogue: scb fp32 [64][132] at 0 (33792B, aliases staging).
    // c2s fp32[128] at 49152 (never aliased). Total 49664 -> 3 blocks/CU.
    __shared__ __align__(16) char smem[49664];
    unsigned short* A0 = (unsigned short*)smem;                   // 4096 shorts/buf
    unsigned short* B0 = (unsigned short*)(smem + 24576);
    float*  scb = (float*)smem;
    float*  c2s = (float*)(smem + 49152);

    const int tid  = threadIdx.x;
    const int wid  = tid >> 6, lane = tid & 63;
    const int quad = lane >> 4, l16 = lane & 15;

    // dispatch-linear id (x fastest); HW round-robins XCD by L%8.
    // mb = (L&7)*16 + (L>>3)/16 -> each XCD owns 16 consecutive mb panels,
    // nb = (L>>3)&15            -> nb iterates fastest within an XCD.
    const int L    = blockIdx.y * NBLK + blockIdx.x;
    const int slot = L >> 3;
    const int mb   = (L & 7) * 16 + (slot >> 4);
    const int nb   = slot & 15;

    const int tok0 = mb * 128, n0 = nb * 128;
    const int nw = (wid & 1) * 64;
    const int fbA = (wid >> 1) * 4;      // base mi for this wave's A rows
    const int fbB = (wid & 1) * 4;       // base nj for this wave's B rows

    if (tid < 128) c2s[tid] = c2[n0 + tid];

    float4v acc[4][4];
    float4v zero = {0.f, 0.f, 0.f, 0.f};
#pragma unroll
    for (int mi = 0; mi < 4; ++mi)
#pragma unroll
        for (int nj = 0; nj < 4; ++nj) acc[mi][nj] = zero;

    // stage tile kb into buffer b (b in 0..2): lane (quad,l16) of wave wid
    // loads row (i*4+wid)*16+l16, k-chunk quad -> LDS slot i*256+wid*64+lane.
    auto stage = [&](int b, int kb) {
        unsigned short* Ad = A0 + b * 4096;
        unsigned short* Bd = B0 + b * 4096;
#pragma unroll
        for (int i = 0; i < 2; ++i) {
            int mi_abs = i * 4 + wid;
            gl2lds16(&Rb[(size_t)(tok0 + mi_abs * 16 + l16) * DIM + kb + quad * 8],
                     Ad + (size_t)(i * 256 + wid * 64) * 8);
            gl2lds16(&Cbb[(size_t)(n0 + mi_abs * 16 + l16) * DIM + kb + quad * 8],
                     Bd + (size_t)(i * 256 + wid * 64) * 8);
        }
    };

    auto compute = [&](int b) {
        const unsigned short* Ac = A0 + b * 4096;
        const unsigned short* Bc = B0 + b * 4096;
        short8 af[4], bf[4];
#pragma unroll
        for (int mi = 0; mi < 4; ++mi)
            af[mi] = *(const short8*)(Ac + ((size_t)(fbA + mi) * 64 + lane) * 8);
#pragma unroll
        for (int nj = 0; nj < 4; ++nj)
            bf[nj] = *(const short8*)(Bc + ((size_t)(fbB + nj) * 64 + lane) * 8);
#pragma unroll
        for (int mi = 0; mi < 4; ++mi)
#pragma unroll
            for (int nj = 0; nj < 4; ++nj)
                acc[mi][nj] = __builtin_amdgcn_mfma_f32_16x16x32_bf16(
                    af[mi], bf[nj], acc[mi][nj], 0, 0, 0);
    };

    // K-loop: at iter it the wave has stage(it) [oldest, maybe outstanding]
    // and stage(it+1) [4 loads] in flight. vmcnt(4) => stage(it) landed;
    // barrier => landed for ALL waves; then stage(it+2) reuses the buffer
    // read at it-1 (all waves past barrier => done reading it).
    stage(0, 0);
    stage(1, 32);
    int cur = 0, pf = 2;
    for (int it = 0; it < 15; ++it) {
        asm volatile("s_waitcnt vmcnt(4)" ::: "memory");
        __builtin_amdgcn_s_barrier();
        __builtin_amdgcn_sched_barrier(0);
        if (it < 14) stage(pf, (it + 2) * 32);
        compute(cur);
        cur = (cur == 2) ? 0 : cur + 1;
        pf  = (pf  == 2) ? 0 : pf  + 1;
    }
    asm volatile("s_waitcnt vmcnt(0)" ::: "memory");
    __builtin_amdgcn_s_barrier();
    __builtin_amdgcn_sched_barrier(0);
    compute(cur);                                   // it = 15, buffer 0

    // epilogue: two 64-row halves; per-row top-4 of sb = c2 - 2*dot.
    // scb stride 132: write bank 16(quad+nj)+4e+l16, read bank 4row+part ->
    // both 2 lanes/bank (free). Part-merge via in-wave shuffles (no LDS).
    // NOTE: partition/insertion order unchanged (bit-exact candidate set).
    for (int h = 0; h < 2; ++h) {
        __syncthreads();
        if ((wid >> 1) == h) {
#pragma unroll
            for (int mi = 0; mi < 4; ++mi)
#pragma unroll
                for (int nj = 0; nj < 4; ++nj) {
                    int r0 = mi * 16 + quad * 4;
                    int cc = nw + nj * 16 + l16;
#pragma unroll
                    for (int e = 0; e < 4; ++e)
                        scb[(r0 + e) * 132 + cc] = acc[mi][nj][e];
                }
        }
        __syncthreads();
        int row = tid >> 2, part = tid & 3;
        Top4 t; t4_init(t);
#pragma unroll
        for (int i = 0; i < 32; ++i) {
            int col = part + 4 * i;
            float s = c2s[col] - 2.0f * scb[row * 132 + col];
            t4_ins(t, s, n0 + col);
        }
        // merge the 4 parts of this row (4 adjacent lanes of one wave)
#pragma unroll
        for (int k = 1; k <= 2; k <<= 1) {
            float os[4]; int oi[4];
#pragma unroll
            for (int j = 0; j < 4; ++j) {
                os[j] = __shfl_xor(t.s[j], k, 64);
                oi[j] = __shfl_xor(t.i[j], k, 64);
            }
#pragma unroll
            for (int j = 0; j < 4; ++j) t4_ins(t, os[j], oi[j]);
        }
        if (part == 0) {
            int token = tok0 + h * 64 + row;
            size_t base = (size_t)token * 64 + (size_t)nb * 4;
#pragma unroll
            for (int j = 0; j < 4; ++j) { candS[base + j] = t.s[j]; candI[base + j] = t.i[j]; }
        }
    }
}

// Fused: select winner (R3-replica exact rescore of in-window candidates),
// update residual, recast bf16, np-ordered r2 for next level, loss partial.
// R10: R row staged once (coalesced) into LDS+regs; rescore reads rp from LDS
// (broadcast) and cp as float4 -- same values, same ascending-k fmaf chain.
__global__ __launch_bounds__(256) void k_selupd(
        const float* __restrict__ candS, const int* __restrict__ candI,
        float* __restrict__ R, const float* __restrict__ cbf,
        float* __restrict__ r2, const float* __restrict__ c2,
        float* __restrict__ idx_out, float* __restrict__ partial,
        ushort4* __restrict__ Rb, const float4* __restrict__ x, int level)
{
#pragma clang fp contract(off)
    __shared__ float buf[4][DIM];
    __shared__ float accs[4][32];
    __shared__ float shl[4];
    const int w = threadIdx.x >> 6, lane = threadIdx.x & 63;
    const int t = blockIdx.x * 4 + w;
    const bool last = (level == NQ - 1);

    // ---- stage R row (coalesced) into regs + per-wave LDS copy ----
    float4* r4 = reinterpret_cast<float4*>(R + (size_t)t * DIM);
    float4* b4 = reinterpret_cast<float4*>(buf[w]);
    float4 rr[2];
    rr[0] = r4[lane];      rr[1] = r4[lane + 64];
    b4[lane] = rr[0];      b4[lane + 64] = rr[1];

    // ---- select ----
    float sb = candS[(size_t)t * 64 + lane];
    int   ci = candI[(size_t)t * 64 + lane];
    float mn = sb;
#pragma unroll
    for (int off = 32; off; off >>= 1) mn = fminf(mn, __shfl_xor(mn, off, 64));
    unsigned long long mask = __ballot(sb <= mn + WINDOW);
    int ncand = __popcll(mask);
    int winner;
    if (ncand == 1) {
        winner = __shfl(ci, __ffsll(mask) - 1, 64);
    } else {
        int src = 0;
        if (lane < ncand) {
            unsigned long long mm = mask;
            for (int z = 0; z < lane; ++z) mm &= mm - 1;
            src = __ffsll(mm) - 1;
        }
        int cidx = __shfl(ci, src, 64);
        float s = 3.0e38f;
        int   si = 0x7FFFFFFF;
        if (lane < ncand) {
            const float4* cp4 = reinterpret_cast<const float4*>(cbf + (size_t)cidx * DIM);
            const float4* rp4 = reinterpret_cast<const float4*>(buf[w]);  // broadcast
            float d = 0.f;
#pragma unroll 4
            for (int j = 0; j < DIM / 4; ++j) {
                float4 cv = cp4[j];
                float4 rv = rp4[j];
                d = fmaf(rv.x, cv.x, d);
                d = fmaf(rv.y, cv.y, d);
                d = fmaf(rv.z, cv.z, d);
                d = fmaf(rv.w, cv.w, d);
            }
            float td = 2.0f * d;
            float a  = r2[t] - td;
            s  = a + c2[cidx];
            si = cidx;
        }
#pragma unroll
        for (int off = 32; off; off >>= 1) {
            float ov = __shfl_xor(s, off, 64);
            int   oi = __shfl_xor(si, off, 64);
            if (ov < s || (ov == s && oi < si)) { s = ov; si = oi; }
        }
        winner = si;
    }
    if (lane == 0) idx_out[(size_t)t * NQ + level] = (float)winner;

    // ---- update (reuses staged rr; values identical to re-reading R) ----
    const float4* c4 = reinterpret_cast<const float4*>(cbf + (size_t)winner * DIM);
    float ls = 0.f;
#pragma unroll
    for (int i = 0; i < 2; ++i) {
        int d = lane + 64 * i;
        float4 rv = rr[i], cv = c4[d];
        rv.x -= cv.x; rv.y -= cv.y; rv.z -= cv.z; rv.w -= cv.w;
        ls = ls + rv.x * rv.x; ls = ls + rv.y * rv.y;
        ls = ls + rv.z * rv.z; ls = ls + rv.w * rv.w;
        if (!last) {
            r4[d] = rv;
            b4[d] = rv;
            Rb[(size_t)t * 128 + d] = make_ushort4(f2bf(rv.x), f2bf(rv.y),
                                                   f2bf(rv.z), f2bf(rv.w));
        } else {
            float4 xv = x[(size_t)t * 128 + d];
            xv.x -= rv.x; xv.y -= rv.y; xv.z -= rv.z; xv.w -= rv.w;
            r4[d] = xv;                       // quantized = x - r_final (in d_out)
        }
    }

    if (!last) {
        __syncthreads();
        // np-pairwise r2 of the NEW residual (same order as k_sqnorm_np)
        if (lane < 32) {
            int blk = lane >> 3, j = lane & 7;
            const float* p = buf[w] + blk * 128 + j;
            float x0 = p[0];
            float acc = x0 * x0;
#pragma unroll
            for (int m = 1; m < 16; ++m) { float xx = p[8 * m]; acc = acc + xx * xx; }
            accs[w][lane] = acc;
        }
        __syncthreads();
        if (lane == 0) {
            float B[4];
#pragma unroll
            for (int blk = 0; blk < 4; ++blk) {
                const float* r = &accs[w][blk * 8];
                B[blk] = ((r[0] + r[1]) + (r[2] + r[3])) + ((r[4] + r[5]) + (r[6] + r[7]));
            }
            r2[t] = (B[0] + B[1]) + (B[2] + B[3]);
        }
    }

    // ---- loss partial ----
#pragma unroll
    for (int off = 32; off; off >>= 1) ls += __shfl_down(ls, off, 64);
    if (lane == 0) shl[w] = ls;
    __syncthreads();
    if (threadIdx.x == 0) partial[blockIdx.x] = (shl[0] + shl[1]) + (shl[2] + shl[3]);
}

__global__ __launch_bounds__(256) void k_finalize_loss(const float* __restrict__ partial,
                                                       float* __restrict__ loss_out)
{
    double s = 0.0;
    for (int i = threadIdx.x; i < NQ * (NTOK / 4); i += 256) s += (double)partial[i];
#pragma unroll
    for (int off = 32; off; off >>= 1) s += __shfl_down(s, off, 64);
    __shared__ double sh[4];
    if ((threadIdx.x & 63) == 0) sh[threadIdx.x >> 6] = s;
    __syncthreads();
    if (threadIdx.x == 0) {
        double tot = (sh[0] + sh[1]) + (sh[2] + sh[3]);
        loss_out[0] = (float)(tot * 1.25 / ((double)NQ * (double)QELEM));
    }
}

extern "C" void kernel_launch(void* const* d_in, const int* in_sizes, int n_in,
                              void* d_out, int out_size, void* d_ws, size_t ws_size,
                              hipStream_t stream)
{
    const float* x   = (const float*)d_in[0];
    const float* cbs = (const float*)d_in[1];

    float* qout     = (float*)d_out;
    float* idx_out  = qout + QELEM;
    float* loss_out = idx_out + (size_t)NTOK * NQ;
    float* R        = qout;                 // residual lives in d_out (validated R5)

    char* ws = (char*)d_ws;
    size_t off = 0;
    unsigned short* Rb   = (unsigned short*)(ws + off); off += (size_t)QELEM * 2;  // 16MB
    unsigned short* Cbb  = (unsigned short*)(ws + off); off += (size_t)QELEM * 2;  // 16MB
    float*          c2   = (float*)(ws + off);          off += (size_t)NQ * KCB * 4;
    float*          r2   = (float*)(ws + off);          off += (size_t)NTOK * 4;
    float*          part = (float*)(ws + off);          off += (size_t)NQ * (NTOK / 4) * 4;
    float*          candS= (float*)(ws + off);          off += (size_t)NTOK * 64 * 4; // 4MB
    int*            candI= (int*)(ws + off);            off += (size_t)NTOK * 64 * 4; // 4MB

    k_initcvt<<<2 * (QELEM / 4) / 256, 256, 0, stream>>>((const float4*)x, (const float4*)cbs,
                                                         (float4*)R, (ushort4*)Rb,
                                                         (ushort4*)Cbb);
    k_sqnorm_np<<<NQ * KCB / 4, 256, 0, stream>>>(cbs, c2);
    k_sqnorm_np<<<NTOK / 4, 256, 0, stream>>>(R, r2);   // r2 of x for level 0

    for (int q = 0; q < NQ; ++q) {
        const float*          cbq  = cbs + (size_t)q * KCB * DIM;
        const unsigned short* cbbq = Cbb + (size_t)q * KCB * DIM;
        const float*          c2q  = c2 + (size_t)q * KCB;
        dim3 g(NBLK, NTOK / 128);
        k_gemm_topk<<<g, 256, 0, stream>>>(Rb, cbbq, c2q, candS, candI);
        k_selupd<<<NTOK / 4, 256, 0, stream>>>(candS, candI, R, cbq, r2, c2q,
                                               idx_out, part + (size_t)q * (NTOK / 4),
                                               (ushort4*)Rb, (const float4*)x, q);
    }

    k_finalize_loss<<<1, 256, 0, stream>>>(part, loss_out);
}

// Round 3
// 1005.505 us; speedup vs baseline: 1.2400x; 1.0357x over previous
//
#include <hip/hip_runtime.h>

// Residual VQ forward, MFMA candidates + R3-replica exact selection. R11:
//  - gemm epilogue: contiguous-col read partition (8x ds_read_b128 per thread
//    instead of 32x b32), c2s hoisted to regs once (8x b128 vs 64x b32/thread),
//    T5 setprio(1) around MFMA cluster. Candidate set provably identical
//    (ascending scan per part + lower-part-wins-ties merge; only part0 writes).
//  - k_initcvt + 2x k_sqnorm_np fused into k_initnorm (row-oriented; verbatim
//    np-pairwise reduction on identical buf contents -> bit-exact r2/c2).
// R10: triple-buffer counted-vmcnt K-loop (~null, kept); selupd coalesced
// R-row staging (+175us). R9: XCD-pinned swizzle (FETCH 67.7->16.6MB, ideal).
// d_out flat: [quantized (B,T,D) | indices (B,T,Q) as float | loss scalar]
// Selection arithmetic (validated R3/R5/R6/R7, bit-exact vs reference):
//   sb = c2 - 2*dot_bf16 candidates (top-4 per 128-code block);
//   exact rescore = ascending 512-step fmaf chain, s = fl(fl(r2-2d)+c2),
//   contract off, lowest-index tie-break; r2/c2 numpy-pairwise order.

constexpr int DIM   = 512;
constexpr int KCB   = 2048;
constexpr int NQ    = 8;
constexpr int NTOK  = 8 * 2048;       // 16384
constexpr int QELEM = NTOK * DIM;     // 8388608
constexpr int NBLK  = KCB / 128;      // 16 column blocks
constexpr float WINDOW = 1e-3f;       // worst-case bf16 score err ~4.5e-4

using short8  = __attribute__((ext_vector_type(8))) short;
using float4v = __attribute__((ext_vector_type(4))) float;

__device__ __forceinline__ unsigned short f2bf(float f) {
    unsigned u = __float_as_uint(f);
    return (unsigned short)((u + 0x7FFFu + ((u >> 16) & 1u)) >> 16);   // RNE
}

__device__ __forceinline__ void gl2lds16(const void* g, void* l) {
    __builtin_amdgcn_global_load_lds(
        (__attribute__((address_space(1))) void*)g,
        (__attribute__((address_space(3))) void*)l, 16, 0, 0);
}

struct Top4 { float s[4]; int i[4]; };
__device__ __forceinline__ void t4_init(Top4& t) {
#pragma unroll
    for (int j = 0; j < 4; ++j) { t.s[j] = 3.0e38f; t.i[j] = 0x7FFFFFFF; }
}
__device__ __forceinline__ void t4_ins(Top4& t, float s, int idx) {
    if (s < t.s[3]) {
        if (s < t.s[2]) { t.s[3] = t.s[2]; t.i[3] = t.i[2];
            if (s < t.s[1]) { t.s[2] = t.s[1]; t.i[2] = t.i[1];
                if (s < t.s[0]) { t.s[1] = t.s[0]; t.i[1] = t.i[0]; t.s[0] = s; t.i[0] = idx; }
                else            { t.s[1] = s; t.i[1] = idx; }
            } else { t.s[2] = s; t.i[2] = idx; }
        } else { t.s[3] = s; t.i[3] = idx; }
    }
}

// Fused init: blocks [0,4096) handle x rows (copy R, cast Rb, np-pairwise r2);
// blocks [4096,8192) handle codebook rows (cast Cbb, np-pairwise c2).
// One wave per row; reduction code verbatim from validated k_sqnorm_np.
__global__ __launch_bounds__(256) void k_initnorm(
        const float* __restrict__ x, const float* __restrict__ cbs,
        float4* __restrict__ R, ushort4* __restrict__ Rb, ushort4* __restrict__ Cbb,
        float* __restrict__ r2, float* __restrict__ c2)
{
#pragma clang fp contract(off)
    __shared__ float buf[4][DIM];
    __shared__ float accs[4][32];
    const int w = threadIdx.x >> 6, lane = threadIdx.x & 63;
    const bool isX = blockIdx.x < (NTOK / 4);
    const int row = (isX ? blockIdx.x : blockIdx.x - NTOK / 4) * 4 + w;

    const float* src = isX ? x : cbs;
    const float4* a4 = reinterpret_cast<const float4*>(src + (size_t)row * DIM);
    float4 v0 = a4[lane], v1 = a4[lane + 64];

    ushort4 b0 = make_ushort4(f2bf(v0.x), f2bf(v0.y), f2bf(v0.z), f2bf(v0.w));
    ushort4 b1 = make_ushort4(f2bf(v1.x), f2bf(v1.y), f2bf(v1.z), f2bf(v1.w));
    if (isX) {
        R [(size_t)row * 128 + lane]      = v0;
        R [(size_t)row * 128 + lane + 64] = v1;
        Rb[(size_t)row * 128 + lane]      = b0;
        Rb[(size_t)row * 128 + lane + 64] = b1;
    } else {
        Cbb[(size_t)row * 128 + lane]      = b0;
        Cbb[(size_t)row * 128 + lane + 64] = b1;
    }

    float4* b4 = reinterpret_cast<float4*>(buf[w]);
    b4[lane]      = v0;
    b4[lane + 64] = v1;
    __syncthreads();
    if (lane < 32) {
        int blk = lane >> 3, j = lane & 7;
        const float* p = buf[w] + blk * 128 + j;
        float x0 = p[0];
        float acc = x0 * x0;
#pragma unroll
        for (int m = 1; m < 16; ++m) { float xx = p[8 * m]; acc = acc + xx * xx; }
        accs[w][lane] = acc;
    }
    __syncthreads();
    if (lane == 0) {
        float B[4];
#pragma unroll
        for (int blk = 0; blk < 4; ++blk) {
            const float* r = &accs[w][blk * 8];
            B[blk] = ((r[0] + r[1]) + (r[2] + r[3])) + ((r[4] + r[5]) + (r[6] + r[7]));
        }
        float out = (B[0] + B[1]) + (B[2] + B[3]);
        if (isX) r2[row] = out; else c2[row] = out;
    }
}

// 128x128 tile bf16 MFMA GEMM (A.B^T) + per-row top-4 over the 128 cols.
// Triple-buffered staging, counted vmcnt(4); R11 vectorized epilogue reads.
__global__ __launch_bounds__(256, 3) void k_gemm_topk(
        const unsigned short* __restrict__ Rb, const unsigned short* __restrict__ Cbb,
        const float* __restrict__ c2, float* __restrict__ candS, int* __restrict__ candI)
{
    // [0,24576): A0|A1|A2 (8KB each).  [24576,49152): B0|B1|B2.
    // Epilogue: scb fp32 [64][132] at 0 (33792B, aliases staging).
    // c2s fp32[128] at 49152 (never aliased). Total 49664 -> 3 blocks/CU.
    __shared__ __align__(16) char smem[49664];
    unsigned short* A0 = (unsigned short*)smem;                   // 4096 shorts/buf
    unsigned short* B0 = (unsigned short*)(smem + 24576);
    float*  scb = (float*)smem;
    float*  c2s = (float*)(smem + 49152);

    const int tid  = threadIdx.x;
    const int wid  = tid >> 6, lane = tid & 63;
    const int quad = lane >> 4, l16 = lane & 15;

    // dispatch-linear id (x fastest); HW round-robins XCD by L%8.
    // mb = (L&7)*16 + (L>>3)/16 -> each XCD owns 16 consecutive mb panels,
    // nb = (L>>3)&15            -> nb iterates fastest within an XCD.
    const int L    = blockIdx.y * NBLK + blockIdx.x;
    const int slot = L >> 3;
    const int mb   = (L & 7) * 16 + (slot >> 4);
    const int nb   = slot & 15;

    const int tok0 = mb * 128, n0 = nb * 128;
    const int nw = (wid & 1) * 64;
    const int fbA = (wid >> 1) * 4;      // base mi for this wave's A rows
    const int fbB = (wid & 1) * 4;       // base nj for this wave's B rows

    if (tid < 128) c2s[tid] = c2[n0 + tid];

    float4v acc[4][4];
    float4v zero = {0.f, 0.f, 0.f, 0.f};
#pragma unroll
    for (int mi = 0; mi < 4; ++mi)
#pragma unroll
        for (int nj = 0; nj < 4; ++nj) acc[mi][nj] = zero;

    // stage tile kb into buffer b (b in 0..2): lane (quad,l16) of wave wid
    // loads row (i*4+wid)*16+l16, k-chunk quad -> LDS slot i*256+wid*64+lane.
    auto stage = [&](int b, int kb) {
        unsigned short* Ad = A0 + b * 4096;
        unsigned short* Bd = B0 + b * 4096;
#pragma unroll
        for (int i = 0; i < 2; ++i) {
            int mi_abs = i * 4 + wid;
            gl2lds16(&Rb[(size_t)(tok0 + mi_abs * 16 + l16) * DIM + kb + quad * 8],
                     Ad + (size_t)(i * 256 + wid * 64) * 8);
            gl2lds16(&Cbb[(size_t)(n0 + mi_abs * 16 + l16) * DIM + kb + quad * 8],
                     Bd + (size_t)(i * 256 + wid * 64) * 8);
        }
    };

    auto compute = [&](int b) {
        const unsigned short* Ac = A0 + b * 4096;
        const unsigned short* Bc = B0 + b * 4096;
        short8 af[4], bf[4];
#pragma unroll
        for (int mi = 0; mi < 4; ++mi)
            af[mi] = *(const short8*)(Ac + ((size_t)(fbA + mi) * 64 + lane) * 8);
#pragma unroll
        for (int nj = 0; nj < 4; ++nj)
            bf[nj] = *(const short8*)(Bc + ((size_t)(fbB + nj) * 64 + lane) * 8);
        __builtin_amdgcn_s_setprio(1);                 // T5: favor MFMA cluster
#pragma unroll
        for (int mi = 0; mi < 4; ++mi)
#pragma unroll
            for (int nj = 0; nj < 4; ++nj)
                acc[mi][nj] = __builtin_amdgcn_mfma_f32_16x16x32_bf16(
                    af[mi], bf[nj], acc[mi][nj], 0, 0, 0);
        __builtin_amdgcn_s_setprio(0);
    };

    // K-loop: at iter it the wave has stage(it) [oldest, maybe outstanding]
    // and stage(it+1) [4 loads] in flight. vmcnt(4) => stage(it) landed;
    // barrier => landed for ALL waves; then stage(it+2) reuses the buffer
    // read at it-1 (all waves past barrier => done reading it).
    stage(0, 0);
    stage(1, 32);
    int cur = 0, pf = 2;
    for (int it = 0; it < 15; ++it) {
        asm volatile("s_waitcnt vmcnt(4)" ::: "memory");
        __builtin_amdgcn_s_barrier();
        __builtin_amdgcn_sched_barrier(0);
        if (it < 14) stage(pf, (it + 2) * 32);
        compute(cur);
        cur = (cur == 2) ? 0 : cur + 1;
        pf  = (pf  == 2) ? 0 : pf  + 1;
    }
    asm volatile("s_waitcnt vmcnt(0)" ::: "memory");
    __builtin_amdgcn_s_barrier();
    __builtin_amdgcn_sched_barrier(0);
    compute(cur);                                   // it = 15, buffer 0

    // epilogue: two 64-row halves; per-row top-4 of sb = c2 - 2*dot.
    // scb row-major stride 132 (writes 2 lanes/bank, free). R11 reads: each
    // part owns 32 CONTIGUOUS cols -> 8x ds_read_b128 (quad-start spread
    // uniform: (row+j) mod 8). c2s hoisted to regs once. Candidate set
    // identical: ascending scan per part, merges keep lower-part on ties,
    // only part==0's result is written.
    const int row_ = tid >> 2, part_ = tid & 3;
    float4 c2r[8];
#pragma unroll
    for (int j = 0; j < 8; ++j)
        c2r[j] = *(const float4*)(c2s + part_ * 32 + 4 * j);

    for (int h = 0; h < 2; ++h) {
        __syncthreads();
        if ((wid >> 1) == h) {
#pragma unroll
            for (int mi = 0; mi < 4; ++mi)
#pragma unroll
                for (int nj = 0; nj < 4; ++nj) {
                    int r0 = mi * 16 + quad * 4;
                    int cc = nw + nj * 16 + l16;
#pragma unroll
                    for (int e = 0; e < 4; ++e)
                        scb[(r0 + e) * 132 + cc] = acc[mi][nj][e];
                }
        }
        __syncthreads();
        Top4 t; t4_init(t);
#pragma unroll
        for (int j = 0; j < 8; ++j) {
            float4 sv = *(const float4*)(scb + row_ * 132 + part_ * 32 + 4 * j);
            float4 cv = c2r[j];
            int c0 = n0 + part_ * 32 + 4 * j;
            t4_ins(t, cv.x - 2.0f * sv.x, c0 + 0);
            t4_ins(t, cv.y - 2.0f * sv.y, c0 + 1);
            t4_ins(t, cv.z - 2.0f * sv.z, c0 + 2);
            t4_ins(t, cv.w - 2.0f * sv.w, c0 + 3);
        }
        // merge the 4 parts of this row (4 adjacent lanes of one wave)
#pragma unroll
        for (int k = 1; k <= 2; k <<= 1) {
            float os[4]; int oi[4];
#pragma unroll
            for (int j = 0; j < 4; ++j) {
                os[j] = __shfl_xor(t.s[j], k, 64);
                oi[j] = __shfl_xor(t.i[j], k, 64);
            }
#pragma unroll
            for (int j = 0; j < 4; ++j) t4_ins(t, os[j], oi[j]);
        }
        if (part_ == 0) {
            int token = tok0 + h * 64 + row_;
            size_t base = (size_t)token * 64 + (size_t)nb * 4;
#pragma unroll
            for (int j = 0; j < 4; ++j) { candS[base + j] = t.s[j]; candI[base + j] = t.i[j]; }
        }
    }
}

// Fused: select winner (R3-replica exact rescore of in-window candidates),
// update residual, recast bf16, np-ordered r2 for next level, loss partial.
// R10: R row staged once (coalesced) into LDS+regs; rescore reads rp from LDS
// (broadcast) and cp as float4 -- same values, same ascending-k fmaf chain.
__global__ __launch_bounds__(256) void k_selupd(
        const float* __restrict__ candS, const int* __restrict__ candI,
        float* __restrict__ R, const float* __restrict__ cbf,
        float* __restrict__ r2, const float* __restrict__ c2,
        float* __restrict__ idx_out, float* __restrict__ partial,
        ushort4* __restrict__ Rb, const float4* __restrict__ x, int level)
{
#pragma clang fp contract(off)
    __shared__ float buf[4][DIM];
    __shared__ float accs[4][32];
    __shared__ float shl[4];
    const int w = threadIdx.x >> 6, lane = threadIdx.x & 63;
    const int t = blockIdx.x * 4 + w;
    const bool last = (level == NQ - 1);

    // ---- stage R row (coalesced) into regs + per-wave LDS copy ----
    float4* r4 = reinterpret_cast<float4*>(R + (size_t)t * DIM);
    float4* b4 = reinterpret_cast<float4*>(buf[w]);
    float4 rr[2];
    rr[0] = r4[lane];      rr[1] = r4[lane + 64];
    b4[lane] = rr[0];      b4[lane + 64] = rr[1];

    // ---- select ----
    float sb = candS[(size_t)t * 64 + lane];
    int   ci = candI[(size_t)t * 64 + lane];
    float mn = sb;
#pragma unroll
    for (int off = 32; off; off >>= 1) mn = fminf(mn, __shfl_xor(mn, off, 64));
    unsigned long long mask = __ballot(sb <= mn + WINDOW);
    int ncand = __popcll(mask);
    int winner;
    if (ncand == 1) {
        winner = __shfl(ci, __ffsll(mask) - 1, 64);
    } else {
        int src = 0;
        if (lane < ncand) {
            unsigned long long mm = mask;
            for (int z = 0; z < lane; ++z) mm &= mm - 1;
            src = __ffsll(mm) - 1;
        }
        int cidx = __shfl(ci, src, 64);
        float s = 3.0e38f;
        int   si = 0x7FFFFFFF;
        if (lane < ncand) {
            const float4* cp4 = reinterpret_cast<const float4*>(cbf + (size_t)cidx * DIM);
            const float4* rp4 = reinterpret_cast<const float4*>(buf[w]);  // broadcast
            float d = 0.f;
#pragma unroll 4
            for (int j = 0; j < DIM / 4; ++j) {
                float4 cv = cp4[j];
                float4 rv = rp4[j];
                d = fmaf(rv.x, cv.x, d);
                d = fmaf(rv.y, cv.y, d);
                d = fmaf(rv.z, cv.z, d);
                d = fmaf(rv.w, cv.w, d);
            }
            float td = 2.0f * d;
            float a  = r2[t] - td;
            s  = a + c2[cidx];
            si = cidx;
        }
#pragma unroll
        for (int off = 32; off; off >>= 1) {
            float ov = __shfl_xor(s, off, 64);
            int   oi = __shfl_xor(si, off, 64);
            if (ov < s || (ov == s && oi < si)) { s = ov; si = oi; }
        }
        winner = si;
    }
    if (lane == 0) idx_out[(size_t)t * NQ + level] = (float)winner;

    // ---- update (reuses staged rr; values identical to re-reading R) ----
    const float4* c4 = reinterpret_cast<const float4*>(cbf + (size_t)winner * DIM);
    float ls = 0.f;
#pragma unroll
    for (int i = 0; i < 2; ++i) {
        int d = lane + 64 * i;
        float4 rv = rr[i], cv = c4[d];
        rv.x -= cv.x; rv.y -= cv.y; rv.z -= cv.z; rv.w -= cv.w;
        ls = ls + rv.x * rv.x; ls = ls + rv.y * rv.y;
        ls = ls + rv.z * rv.z; ls = ls + rv.w * rv.w;
        if (!last) {
            r4[d] = rv;
            b4[d] = rv;
            Rb[(size_t)t * 128 + d] = make_ushort4(f2bf(rv.x), f2bf(rv.y),
                                                   f2bf(rv.z), f2bf(rv.w));
        } else {
            float4 xv = x[(size_t)t * 128 + d];
            xv.x -= rv.x; xv.y -= rv.y; xv.z -= rv.z; xv.w -= rv.w;
            r4[d] = xv;                       // quantized = x - r_final (in d_out)
        }
    }

    if (!last) {
        __syncthreads();
        // np-pairwise r2 of the NEW residual (same order as k_sqnorm_np)
        if (lane < 32) {
            int blk = lane >> 3, j = lane & 7;
            const float* p = buf[w] + blk * 128 + j;
            float x0 = p[0];
            float acc = x0 * x0;
#pragma unroll
            for (int m = 1; m < 16; ++m) { float xx = p[8 * m]; acc = acc + xx * xx; }
            accs[w][lane] = acc;
        }
        __syncthreads();
        if (lane == 0) {
            float B[4];
#pragma unroll
            for (int blk = 0; blk < 4; ++blk) {
                const float* r = &accs[w][blk * 8];
                B[blk] = ((r[0] + r[1]) + (r[2] + r[3])) + ((r[4] + r[5]) + (r[6] + r[7]));
            }
            r2[t] = (B[0] + B[1]) + (B[2] + B[3]);
        }
    }

    // ---- loss partial ----
#pragma unroll
    for (int off = 32; off; off >>= 1) ls += __shfl_down(ls, off, 64);
    if (lane == 0) shl[w] = ls;
    __syncthreads();
    if (threadIdx.x == 0) partial[blockIdx.x] = (shl[0] + shl[1]) + (shl[2] + shl[3]);
}

__global__ __launch_bounds__(256) void k_finalize_loss(const float* __restrict__ partial,
                                                       float* __restrict__ loss_out)
{
    double s = 0.0;
    for (int i = threadIdx.x; i < NQ * (NTOK / 4); i += 256) s += (double)partial[i];
#pragma unroll
    for (int off = 32; off; off >>= 1) s += __shfl_down(s, off, 64);
    __shared__ double sh[4];
    if ((threadIdx.x & 63) == 0) sh[threadIdx.x >> 6] = s;
    __syncthreads();
    if (threadIdx.x == 0) {
        double tot = (sh[0] + sh[1]) + (sh[2] + sh[3]);
        loss_out[0] = (float)(tot * 1.25 / ((double)NQ * (double)QELEM));
    }
}

extern "C" void kernel_launch(void* const* d_in, const int* in_sizes, int n_in,
                              void* d_out, int out_size, void* d_ws, size_t ws_size,
                              hipStream_t stream)
{
    const float* x   = (const float*)d_in[0];
    const float* cbs = (const float*)d_in[1];

    float* qout     = (float*)d_out;
    float* idx_out  = qout + QELEM;
    float* loss_out = idx_out + (size_t)NTOK * NQ;
    float* R        = qout;                 // residual lives in d_out (validated R5)

    char* ws = (char*)d_ws;
    size_t off = 0;
    unsigned short* Rb   = (unsigned short*)(ws + off); off += (size_t)QELEM * 2;  // 16MB
    unsigned short* Cbb  = (unsigned short*)(ws + off); off += (size_t)QELEM * 2;  // 16MB
    float*          c2   = (float*)(ws + off);          off += (size_t)NQ * KCB * 4;
    float*          r2   = (float*)(ws + off);          off += (size_t)NTOK * 4;
    float*          part = (float*)(ws + off);          off += (size_t)NQ * (NTOK / 4) * 4;
    float*          candS= (float*)(ws + off);          off += (size_t)NTOK * 64 * 4; // 4MB
    int*            candI= (int*)(ws + off);            off += (size_t)NTOK * 64 * 4; // 4MB

    // fused init: x rows (R copy, Rb cast, r2) + cb rows (Cbb cast, c2)
    k_initnorm<<<NTOK / 4 + NQ * KCB / 4, 256, 0, stream>>>(
        x, cbs, (float4*)R, (ushort4*)Rb, (ushort4*)Cbb, r2, c2);

    for (int q = 0; q < NQ; ++q) {
        const float*          cbq  = cbs + (size_t)q * KCB * DIM;
        const unsigned short* cbbq = Cbb + (size_t)q * KCB * DIM;
        const float*          c2q  = c2 + (size_t)q * KCB;
        dim3 g(NBLK, NTOK / 128);
        k_gemm_topk<<<g, 256, 0, stream>>>(Rb, cbbq, c2q, candS, candI);
        k_selupd<<<NTOK / 4, 256, 0, stream>>>(candS, candI, R, cbq, r2, c2q,
                                               idx_out, part + (size_t)q * (NTOK / 4),
                                               (ushort4*)Rb, (const float4*)x, q);
    }

    k_finalize_loss<<<1, 256, 0, stream>>>(part, loss_out);
}

// Round 4
// 992.584 us; speedup vs baseline: 1.2562x; 1.0130x over previous
//
#include <hip/hip_runtime.h>

// Residual VQ forward, MFMA candidates + R3-replica exact selection. R12:
//  - k_gemm_topk regeometried: 256x256 tile, BK=32, 8 waves (2x4, each 128x64
//    out), triple-buffered staging with the SAME proven vmcnt(4) ledger as
//    R10 (4 gl2lds/wave/iter). Halves staging+barriers per FLOP, 12 ds_reads
//    feed 32 MFMAs (was 8->16). LDS 99328 -> 1 block/CU, 8 waves.
//    Accumulation order per acc[mi][nj] is the identical ascending k=0..480
//    chain of 16x16x32 mfma on identical operands -> scores BIT-IDENTICAL,
//    candidate discipline unchanged -> outputs bit-identical to R11.
//  - epilogue: 4 row-quarters (64x256) via scb stride 260 (write 2 lanes/bank
//    like stride-132), same 4-part contiguous scan + xor-merge per 128-block.
// R11: fused init, vectorized epilogue reads, setprio. R10: counted-vmcnt
// triple buffer; selupd coalesced staging. R9: XCD-pinned swizzle (FETCH ideal).
// d_out flat: [quantized (B,T,D) | indices (B,T,Q) as float | loss scalar]
// Selection arithmetic (validated R3/R5/R6/R7, bit-exact vs reference):
//   sb = c2 - 2*dot_bf16 candidates (top-4 per 128-code block);
//   exact rescore = ascending 512-step fmaf chain, s = fl(fl(r2-2d)+c2),
//   contract off, lowest-index tie-break; r2/c2 numpy-pairwise order.

constexpr int DIM   = 512;
constexpr int KCB   = 2048;
constexpr int NQ    = 8;
constexpr int NTOK  = 8 * 2048;       // 16384
constexpr int QELEM = NTOK * DIM;     // 8388608
constexpr int NBLK2 = KCB / 256;      // 8 column tiles (256 wide)
constexpr float WINDOW = 1e-3f;       // worst-case bf16 score err ~4.5e-4

using short8  = __attribute__((ext_vector_type(8))) short;
using float4v = __attribute__((ext_vector_type(4))) float;

__device__ __forceinline__ unsigned short f2bf(float f) {
    unsigned u = __float_as_uint(f);
    return (unsigned short)((u + 0x7FFFu + ((u >> 16) & 1u)) >> 16);   // RNE
}

__device__ __forceinline__ void gl2lds16(const void* g, void* l) {
    __builtin_amdgcn_global_load_lds(
        (__attribute__((address_space(1))) void*)g,
        (__attribute__((address_space(3))) void*)l, 16, 0, 0);
}

struct Top4 { float s[4]; int i[4]; };
__device__ __forceinline__ void t4_init(Top4& t) {
#pragma unroll
    for (int j = 0; j < 4; ++j) { t.s[j] = 3.0e38f; t.i[j] = 0x7FFFFFFF; }
}
__device__ __forceinline__ void t4_ins(Top4& t, float s, int idx) {
    if (s < t.s[3]) {
        if (s < t.s[2]) { t.s[3] = t.s[2]; t.i[3] = t.i[2];
            if (s < t.s[1]) { t.s[2] = t.s[1]; t.i[2] = t.i[1];
                if (s < t.s[0]) { t.s[1] = t.s[0]; t.i[1] = t.i[0]; t.s[0] = s; t.i[0] = idx; }
                else            { t.s[1] = s; t.i[1] = idx; }
            } else { t.s[2] = s; t.i[2] = idx; }
        } else { t.s[3] = s; t.i[3] = idx; }
    }
}

// Fused init: blocks [0,4096) handle x rows (copy R, cast Rb, np-pairwise r2);
// blocks [4096,8192) handle codebook rows (cast Cbb, np-pairwise c2).
__global__ __launch_bounds__(256) void k_initnorm(
        const float* __restrict__ x, const float* __restrict__ cbs,
        float4* __restrict__ R, ushort4* __restrict__ Rb, ushort4* __restrict__ Cbb,
        float* __restrict__ r2, float* __restrict__ c2)
{
#pragma clang fp contract(off)
    __shared__ float buf[4][DIM];
    __shared__ float accs[4][32];
    const int w = threadIdx.x >> 6, lane = threadIdx.x & 63;
    const bool isX = blockIdx.x < (NTOK / 4);
    const int row = (isX ? blockIdx.x : blockIdx.x - NTOK / 4) * 4 + w;

    const float* src = isX ? x : cbs;
    const float4* a4 = reinterpret_cast<const float4*>(src + (size_t)row * DIM);
    float4 v0 = a4[lane], v1 = a4[lane + 64];

    ushort4 b0 = make_ushort4(f2bf(v0.x), f2bf(v0.y), f2bf(v0.z), f2bf(v0.w));
    ushort4 b1 = make_ushort4(f2bf(v1.x), f2bf(v1.y), f2bf(v1.z), f2bf(v1.w));
    if (isX) {
        R [(size_t)row * 128 + lane]      = v0;
        R [(size_t)row * 128 + lane + 64] = v1;
        Rb[(size_t)row * 128 + lane]      = b0;
        Rb[(size_t)row * 128 + lane + 64] = b1;
    } else {
        Cbb[(size_t)row * 128 + lane]      = b0;
        Cbb[(size_t)row * 128 + lane + 64] = b1;
    }

    float4* b4 = reinterpret_cast<float4*>(buf[w]);
    b4[lane]      = v0;
    b4[lane + 64] = v1;
    __syncthreads();
    if (lane < 32) {
        int blk = lane >> 3, j = lane & 7;
        const float* p = buf[w] + blk * 128 + j;
        float x0 = p[0];
        float acc = x0 * x0;
#pragma unroll
        for (int m = 1; m < 16; ++m) { float xx = p[8 * m]; acc = acc + xx * xx; }
        accs[w][lane] = acc;
    }
    __syncthreads();
    if (lane == 0) {
        float B[4];
#pragma unroll
        for (int blk = 0; blk < 4; ++blk) {
            const float* r = &accs[w][blk * 8];
            B[blk] = ((r[0] + r[1]) + (r[2] + r[3])) + ((r[4] + r[5]) + (r[6] + r[7]));
        }
        float out = (B[0] + B[1]) + (B[2] + B[3]);
        if (isX) r2[row] = out; else c2[row] = out;
    }
}

// 256x256 tile bf16 MFMA GEMM (A.B^T) + per-row top-4 per 128-col block.
// 8 waves: wave (wr=wid>>2, wc=wid&3) owns rows wr*128+mi*16 (mi 0..7),
// cols wc*64+nj*16 (nj 0..3). Fragment-unit LDS (1KB per 16-row x 32-k unit).
__global__ __launch_bounds__(512, 2) void k_gemm_topk(
        const unsigned short* __restrict__ Rb, const unsigned short* __restrict__ Cbb,
        const float* __restrict__ c2, float* __restrict__ candS, int* __restrict__ candI)
{
    // A bufs: [0,49152) = A0|A1|A2 (16KB each). B bufs: [49152,98304).
    // c2s fp32[256] at 98304 (never aliased). scb fp32 [64][260] aliases
    // staging post-K-loop (66560B). Total 99328 -> 1 block/CU, 8 waves.
    __shared__ __align__(16) char smem[99328];
    unsigned short* As = (unsigned short*)smem;
    unsigned short* Bs = (unsigned short*)(smem + 49152);
    float*  scb = (float*)smem;
    float*  c2s = (float*)(smem + 98304);

    const int tid  = threadIdx.x;
    const int wid  = tid >> 6, lane = tid & 63;
    const int quad = lane >> 4, l16 = lane & 15;
    const int wr = wid >> 2, wc = wid & 3;

    // XCD pinning: L%8 = HW XCD round-robin; each XCD owns 8 row-panels,
    // col-tile nb2 iterates fastest. Bijective on [0,512).
    const int L    = blockIdx.y * NBLK2 + blockIdx.x;
    const int slot = L >> 3;
    const int mb   = (L & 7) * 8 + (slot >> 3);   // 0..63 row panel
    const int nb2  = slot & 7;                    // 0..7 col tile (256 wide)

    const int tok0 = mb * 256, n0 = nb2 * 256;

    if (tid < 256) c2s[tid] = c2[n0 + tid];

    float4v acc[8][4];
    float4v zero = {0.f, 0.f, 0.f, 0.f};
#pragma unroll
    for (int mi = 0; mi < 8; ++mi)
#pragma unroll
        for (int nj = 0; nj < 4; ++nj) acc[mi][nj] = zero;

    // stage K-tile kb into buffer b3: wave wid stages A units {wid*2, wid*2+1}
    // and B units {wid*2, wid*2+1}. Unit g = 16-row group: lane (quad,l16)
    // loads row g*16+l16, k-chunk quad -> LDS unit base g*1024B (+lane*16 HW).
    // Exactly 4 gl2lds per wave per stage -> same vmcnt(4) ledger as R10.
    auto stage = [&](int b3, int kb) {
        unsigned short* Ad = As + b3 * 8192;
        unsigned short* Bd = Bs + b3 * 8192;
#pragma unroll
        for (int c = 0; c < 2; ++c) {
            int g = wid * 2 + c;
            gl2lds16(&Rb[(size_t)(tok0 + g * 16 + l16) * DIM + kb + quad * 8],
                     Ad + (size_t)(g * 64) * 8);
        }
#pragma unroll
        for (int c = 0; c < 2; ++c) {
            int g = wid * 2 + c;
            gl2lds16(&Cbb[(size_t)(n0 + g * 16 + l16) * DIM + kb + quad * 8],
                     Bd + (size_t)(g * 64) * 8);
        }
    };

    auto compute = [&](int b3) {
        const unsigned short* Ac = As + b3 * 8192;
        const unsigned short* Bc = Bs + b3 * 8192;
        short8 af[8], bf[4];
#pragma unroll
        for (int mi = 0; mi < 8; ++mi)
            af[mi] = *(const short8*)(Ac + ((size_t)(wr * 8 + mi) * 64 + lane) * 8);
#pragma unroll
        for (int nj = 0; nj < 4; ++nj)
            bf[nj] = *(const short8*)(Bc + ((size_t)(wc * 4 + nj) * 64 + lane) * 8);
        __builtin_amdgcn_s_setprio(1);                 // T5
#pragma unroll
        for (int mi = 0; mi < 8; ++mi)
#pragma unroll
            for (int nj = 0; nj < 4; ++nj)
                acc[mi][nj] = __builtin_amdgcn_mfma_f32_16x16x32_bf16(
                    af[mi], bf[nj], acc[mi][nj], 0, 0, 0);
        __builtin_amdgcn_s_setprio(0);
    };

    // K-loop (identical ledger to R10): per iter each wave issues 4 gl2lds;
    // vmcnt(4) => stage(it) landed (stage(it+1)'s 4 are the newest); barrier
    // => landed for ALL waves; stage(it+2) reuses the buffer read at it-1
    // (all waves past barrier => done reading it).
    stage(0, 0);
    stage(1, 32);
    for (int it = 0; it < 16; ++it) {
        if (it < 15) asm volatile("s_waitcnt vmcnt(4)" ::: "memory");
        else         asm volatile("s_waitcnt vmcnt(0)" ::: "memory");
        __builtin_amdgcn_s_barrier();
        __builtin_amdgcn_sched_barrier(0);
        if (it < 14) stage((it + 2) % 3, (it + 2) * 32);
        compute(it % 3);
    }

    // epilogue: 4 row-quarters of 64 rows x 256 cols through scb stride 260.
    // write bank = (4r + c) mod 32 with r = ..+quad*4+e -> 16quad+l16 mod 32
    // -> 2 lanes/bank (free), same math as validated stride-132.
    // read: thread (row=tid>>3, pp=tid&7): block b=pp>>2, part=pp&3 owns 32
    // contiguous cols of its 128-block; ascending scan + xor(1,2) merge over
    // the 4 parts (same discipline as R11 -> identical candidate set).
    const int row_ = tid >> 3, pp = tid & 7;
    float4 c2r[8];
#pragma unroll
    for (int j = 0; j < 8; ++j)
        c2r[j] = *(const float4*)(c2s + pp * 32 + 4 * j);

#pragma unroll
    for (int qr = 0; qr < 4; ++qr) {
        __syncthreads();
        if (wr == (qr >> 1)) {
            const int mi0 = (qr & 1) * 4;
#pragma unroll
            for (int mm = 0; mm < 4; ++mm)
#pragma unroll
                for (int nj = 0; nj < 4; ++nj) {
                    int r0 = mm * 16 + quad * 4;
                    int cc = wc * 64 + nj * 16 + l16;
#pragma unroll
                    for (int e = 0; e < 4; ++e)
                        scb[(r0 + e) * 260 + cc] = acc[mi0 + mm][nj][e];
                }
        }
        __syncthreads();
        Top4 t; t4_init(t);
#pragma unroll
        for (int j = 0; j < 8; ++j) {
            float4 sv = *(const float4*)(scb + row_ * 260 + pp * 32 + 4 * j);
            float4 cv = c2r[j];
            int c0 = n0 + pp * 32 + 4 * j;
            t4_ins(t, cv.x - 2.0f * sv.x, c0 + 0);
            t4_ins(t, cv.y - 2.0f * sv.y, c0 + 1);
            t4_ins(t, cv.z - 2.0f * sv.z, c0 + 2);
            t4_ins(t, cv.w - 2.0f * sv.w, c0 + 3);
        }
        // merge the 4 parts of this (row, block): xor 1,2 stays within the
        // 4-part group and within the row (row = wid*8 + (lane>>3)).
#pragma unroll
        for (int k = 1; k <= 2; k <<= 1) {
            float os[4]; int oi[4];
#pragma unroll
            for (int j = 0; j < 4; ++j) {
                os[j] = __shfl_xor(t.s[j], k, 64);
                oi[j] = __shfl_xor(t.i[j], k, 64);
            }
#pragma unroll
            for (int j = 0; j < 4; ++j) t4_ins(t, os[j], oi[j]);
        }
        if ((pp & 3) == 0) {
            int token = tok0 + qr * 64 + row_;
            int nb = nb2 * 2 + (pp >> 2);
            size_t base = (size_t)token * 64 + (size_t)nb * 4;
#pragma unroll
            for (int j = 0; j < 4; ++j) { candS[base + j] = t.s[j]; candI[base + j] = t.i[j]; }
        }
    }
}

// Fused: select winner (R3-replica exact rescore of in-window candidates),
// update residual, recast bf16, np-ordered r2 for next level, loss partial.
__global__ __launch_bounds__(256) void k_selupd(
        const float* __restrict__ candS, const int* __restrict__ candI,
        float* __restrict__ R, const float* __restrict__ cbf,
        float* __restrict__ r2, const float* __restrict__ c2,
        float* __restrict__ idx_out, float* __restrict__ partial,
        ushort4* __restrict__ Rb, const float4* __restrict__ x, int level)
{
#pragma clang fp contract(off)
    __shared__ float buf[4][DIM];
    __shared__ float accs[4][32];
    __shared__ float shl[4];
    const int w = threadIdx.x >> 6, lane = threadIdx.x & 63;
    const int t = blockIdx.x * 4 + w;
    const bool last = (level == NQ - 1);

    // ---- stage R row (coalesced) into regs + per-wave LDS copy ----
    float4* r4 = reinterpret_cast<float4*>(R + (size_t)t * DIM);
    float4* b4 = reinterpret_cast<float4*>(buf[w]);
    float4 rr[2];
    rr[0] = r4[lane];      rr[1] = r4[lane + 64];
    b4[lane] = rr[0];      b4[lane + 64] = rr[1];

    // ---- select ----
    float sb = candS[(size_t)t * 64 + lane];
    int   ci = candI[(size_t)t * 64 + lane];
    float mn = sb;
#pragma unroll
    for (int off = 32; off; off >>= 1) mn = fminf(mn, __shfl_xor(mn, off, 64));
    unsigned long long mask = __ballot(sb <= mn + WINDOW);
    int ncand = __popcll(mask);
    int winner;
    if (ncand == 1) {
        winner = __shfl(ci, __ffsll(mask) - 1, 64);
    } else {
        int src = 0;
        if (lane < ncand) {
            unsigned long long mm = mask;
            for (int z = 0; z < lane; ++z) mm &= mm - 1;
            src = __ffsll(mm) - 1;
        }
        int cidx = __shfl(ci, src, 64);
        float s = 3.0e38f;
        int   si = 0x7FFFFFFF;
        if (lane < ncand) {
            const float4* cp4 = reinterpret_cast<const float4*>(cbf + (size_t)cidx * DIM);
            const float4* rp4 = reinterpret_cast<const float4*>(buf[w]);  // broadcast
            float d = 0.f;
#pragma unroll 4
            for (int j = 0; j < DIM / 4; ++j) {
                float4 cv = cp4[j];
                float4 rv = rp4[j];
                d = fmaf(rv.x, cv.x, d);
                d = fmaf(rv.y, cv.y, d);
                d = fmaf(rv.z, cv.z, d);
                d = fmaf(rv.w, cv.w, d);
            }
            float td = 2.0f * d;
            float a  = r2[t] - td;
            s  = a + c2[cidx];
            si = cidx;
        }
#pragma unroll
        for (int off = 32; off; off >>= 1) {
            float ov = __shfl_xor(s, off, 64);
            int   oi = __shfl_xor(si, off, 64);
            if (ov < s || (ov == s && oi < si)) { s = ov; si = oi; }
        }
        winner = si;
    }
    if (lane == 0) idx_out[(size_t)t * NQ + level] = (float)winner;

    // ---- update (reuses staged rr; values identical to re-reading R) ----
    const float4* c4 = reinterpret_cast<const float4*>(cbf + (size_t)winner * DIM);
    float ls = 0.f;
#pragma unroll
    for (int i = 0; i < 2; ++i) {
        int d = lane + 64 * i;
        float4 rv = rr[i], cv = c4[d];
        rv.x -= cv.x; rv.y -= cv.y; rv.z -= cv.z; rv.w -= cv.w;
        ls = ls + rv.x * rv.x; ls = ls + rv.y * rv.y;
        ls = ls + rv.z * rv.z; ls = ls + rv.w * rv.w;
        if (!last) {
            r4[d] = rv;
            b4[d] = rv;
            Rb[(size_t)t * 128 + d] = make_ushort4(f2bf(rv.x), f2bf(rv.y),
                                                   f2bf(rv.z), f2bf(rv.w));
        } else {
            float4 xv = x[(size_t)t * 128 + d];
            xv.x -= rv.x; xv.y -= rv.y; xv.z -= rv.z; xv.w -= rv.w;
            r4[d] = xv;                       // quantized = x - r_final (in d_out)
        }
    }

    if (!last) {
        __syncthreads();
        // np-pairwise r2 of the NEW residual (same order as k_initnorm)
        if (lane < 32) {
            int blk = lane >> 3, j = lane & 7;
            const float* p = buf[w] + blk * 128 + j;
            float x0 = p[0];
            float acc = x0 * x0;
#pragma unroll
            for (int m = 1; m < 16; ++m) { float xx = p[8 * m]; acc = acc + xx * xx; }
            accs[w][lane] = acc;
        }
        __syncthreads();
        if (lane == 0) {
            float B[4];
#pragma unroll
            for (int blk = 0; blk < 4; ++blk) {
                const float* r = &accs[w][blk * 8];
                B[blk] = ((r[0] + r[1]) + (r[2] + r[3])) + ((r[4] + r[5]) + (r[6] + r[7]));
            }
            r2[t] = (B[0] + B[1]) + (B[2] + B[3]);
        }
    }

    // ---- loss partial ----
#pragma unroll
    for (int off = 32; off; off >>= 1) ls += __shfl_down(ls, off, 64);
    if (lane == 0) shl[w] = ls;
    __syncthreads();
    if (threadIdx.x == 0) partial[blockIdx.x] = (shl[0] + shl[1]) + (shl[2] + shl[3]);
}

__global__ __launch_bounds__(256) void k_finalize_loss(const float* __restrict__ partial,
                                                       float* __restrict__ loss_out)
{
    double s = 0.0;
    for (int i = threadIdx.x; i < NQ * (NTOK / 4); i += 256) s += (double)partial[i];
#pragma unroll
    for (int off = 32; off; off >>= 1) s += __shfl_down(s, off, 64);
    __shared__ double sh[4];
    if ((threadIdx.x & 63) == 0) sh[threadIdx.x >> 6] = s;
    __syncthreads();
    if (threadIdx.x == 0) {
        double tot = (sh[0] + sh[1]) + (sh[2] + sh[3]);
        loss_out[0] = (float)(tot * 1.25 / ((double)NQ * (double)QELEM));
    }
}

extern "C" void kernel_launch(void* const* d_in, const int* in_sizes, int n_in,
                              void* d_out, int out_size, void* d_ws, size_t ws_size,
                              hipStream_t stream)
{
    const float* x   = (const float*)d_in[0];
    const float* cbs = (const float*)d_in[1];

    float* qout     = (float*)d_out;
    float* idx_out  = qout + QELEM;
    float* loss_out = idx_out + (size_t)NTOK * NQ;
    float* R        = qout;                 // residual lives in d_out (validated R5)

    char* ws = (char*)d_ws;
    size_t off = 0;
    unsigned short* Rb   = (unsigned short*)(ws + off); off += (size_t)QELEM * 2;  // 16MB
    unsigned short* Cbb  = (unsigned short*)(ws + off); off += (size_t)QELEM * 2;  // 16MB
    float*          c2   = (float*)(ws + off);          off += (size_t)NQ * KCB * 4;
    float*          r2   = (float*)(ws + off);          off += (size_t)NTOK * 4;
    float*          part = (float*)(ws + off);          off += (size_t)NQ * (NTOK / 4) * 4;
    float*          candS= (float*)(ws + off);          off += (size_t)NTOK * 64 * 4; // 4MB
    int*            candI= (int*)(ws + off);            off += (size_t)NTOK * 64 * 4; // 4MB

    // fused init: x rows (R copy, Rb cast, r2) + cb rows (Cbb cast, c2)
    k_initnorm<<<NTOK / 4 + NQ * KCB / 4, 256, 0, stream>>>(
        x, cbs, (float4*)R, (ushort4*)Rb, (ushort4*)Cbb, r2, c2);

    for (int q = 0; q < NQ; ++q) {
        const float*          cbq  = cbs + (size_t)q * KCB * DIM;
        const unsigned short* cbbq = Cbb + (size_t)q * KCB * DIM;
        const float*          c2q  = c2 + (size_t)q * KCB;
        dim3 g(NBLK2, NTOK / 256);
        k_gemm_topk<<<g, 512, 0, stream>>>(Rb, cbbq, c2q, candS, candI);
        k_selupd<<<NTOK / 4, 256, 0, stream>>>(candS, candI, R, cbq, r2, c2q,
                                               idx_out, part + (size_t)q * (NTOK / 4),
                                               (ushort4*)Rb, (const float4*)x, q);
    }

    k_finalize_loss<<<1, 256, 0, stream>>>(part, loss_out);
}